// Round 10
// baseline (330.913 us; speedup 1.0000x reference)
//
#include <hip/hip_runtime.h>

#define S_LEN 2048
#define DIM   4096
#define NH    32
#define NKV   8
#define HD    128
#define QST   6144   // packed QKV row stride (Q | K | V)

typedef unsigned short u16;
typedef unsigned int   u32;
typedef __bf16 bf16x8 __attribute__((ext_vector_type(8)));
typedef float  f32x4  __attribute__((ext_vector_type(4)));
typedef float  f32x16 __attribute__((ext_vector_type(16)));

__device__ __forceinline__ u16 f2bf(float f) {
  unsigned u = __float_as_uint(f);
  u += 0x7FFFu + ((u >> 16) & 1u);   // RNE
  return (u16)(u >> 16);
}
__device__ __forceinline__ float bf2f(u16 v) {
  return __uint_as_float(((unsigned)v) << 16);
}
__device__ __forceinline__ void async16(void* lds, const void* g) {
  __builtin_amdgcn_global_load_lds((const __attribute__((address_space(1))) void*)g,
                                   (__attribute__((address_space(3))) void*)lds,
                                   16, 0, 0);
}
#define MFMA16(a, b, c) __builtin_amdgcn_mfma_f32_16x16x32_bf16((a), (b), (c), 0, 0, 0)

// ------------- fused f32->bf16 convert (all 5 tensors) + RoPE table -------------
__global__ void conv_all(const float* __restrict__ x,  const float* __restrict__ wq,
                         const float* __restrict__ wk, const float* __restrict__ wv,
                         const float* __restrict__ wo,
                         u16* __restrict__ xb, u16* __restrict__ wqkvb,
                         u16* __restrict__ wob,
                         float* __restrict__ cs, float* __restrict__ sn) {
  const int stride = gridDim.x * blockDim.x;
  for (int i = blockIdx.x * blockDim.x + threadIdx.x; i < 12713984; i += stride) {
    if (i < 12582912) {
      const float* src; u16* dst; int off;
      if (i < 2097152)      { src = x;  dst = xb;               off = i; }
      else if (i < 6291456) { src = wq; dst = wqkvb;            off = i - 2097152; }
      else if (i < 7340032) { src = wk; dst = wqkvb + 16777216; off = i - 6291456; }
      else if (i < 8388608) { src = wv; dst = wqkvb + 20971520; off = i - 7340032; }
      else                  { src = wo; dst = wob;              off = i - 8388608; }
      float4 v = ((const float4*)src)[off];
      ((ushort4*)dst)[off] = make_ushort4(f2bf(v.x), f2bf(v.y), f2bf(v.z), f2bf(v.w));
    } else {
      int li = i - 12582912;            // RoPE table: S_LEN*64 entries
      int fi = li & 63, t = li >> 6;
      float freq = powf(500000.0f, -(float)(2 * fi) / 128.0f);
      float ang = (float)t * freq;
      cs[li] = cosf(ang);
      sn[li] = sinf(ang);
    }
  }
}

// ---------------- RoPE in-place on packed QKV, K region only ----------------
// (Q-RoPE is fused into attn's Q load.)
__global__ void rope_k(u16* __restrict__ QKVb, const float* __restrict__ cs,
                       const float* __restrict__ sn) {
  int idx = blockIdx.x * blockDim.x + threadIdx.x;
  if (idx >= 1048576) return;
  int i = idx & 63;
  int tmp = idx >> 6;
  int hh = tmp & 7;
  int t  = tmp >> 3;
  u16* p = QKVb + (size_t)t * QST + 4096 + hh * HD + 2 * i;
  float c = cs[t * 64 + i], s = sn[t * 64 + i];
  float te = bf2f(p[0]), to = bf2f(p[1]);
  p[0] = f2bf(te * c - to * s);
  p[1] = f2bf(te * s + to * c);
}

// ======== 256 x (NB*64) 8-wave GEMM, BK=64, 2 phases/K-tile, counted vmcnt ====
// C[m,n] = sum_k A[m,k]*B[n,k].  512 thr = 8 waves (wr 0..1, wc 0..3).
// Per-wave output 128 x NB*16.  NB=4 raises MFMA:ds_read_b128 ratio to 2.67
// (64 MFMA vs 24 b128 per K-tile/wave) vs 2.18 at NB=3 -- LDS-read port was
// the binding resource (theory, r9).  Wait-chain (audited, all NB):
//   prologue vmcnt(2) leaves A1-tail; P0 vmcnt(NB+2) retires old A1';
//   P1 vmcnt(2) retires A0''+B'', leaves A1''.  Never 0 mid-loop.
// 16B-slot swizzle slot^=(row&7) both-sides -> 0 bank conflicts (verified).
template<int NB, int OUT_BF16>
__device__ __forceinline__ void gemm256_body(const u16* __restrict__ A,
                                             const u16* __restrict__ Bm,
                                             void* __restrict__ Cout,
                                             int m0, int n0, int Nst, int Ks) {
  constexpr int BSZ  = NB * 4096;        // B u16 per buffer
  constexpr int SBUF = 16384 + BSZ;      // u16 per buffer
  __shared__ alignas(16) u16 lds[2 * SBUF];
  const int tid = threadIdx.x;
  const int w = tid >> 6, lane = tid & 63;
  const int lrow = lane & 15, lk = lane >> 4;
  const int wr = w >> 2, wc = w & 3;
  f32x4 acc[2][4][NB] = {};

  const int srow = tid >> 3;                 // staging row 0..63
  const int scol = (tid & 7) ^ (srow & 7);   // pre-swizzled source 16B slot
  const u16* Ag = A + (size_t)m0 * Ks;
  const u16* Bg = Bm + (size_t)n0 * Ks;

  const int sl0 = (lk ^ (lrow & 7)) * 8;     // kk=0 swizzled slot (u16)
  const int sl1 = ((4 + lk) ^ (lrow & 7)) * 8;
  const int aro = (wr * 64 + lrow) * 64;     // + mi*1024, within 128-row half
  const int bro = (wc * (NB * 16) + lrow) * 64;  // + ni*1024
  const int nkt = Ks >> 6;

#define STAGE_A(dst_u16, gbase) do { \
    const u16* _g = (gbase) + (size_t)srow * Ks + scol * 8; \
    async16(&lds[(dst_u16) + tid * 8], _g); \
    async16(&lds[(dst_u16) + tid * 8 + 4096], _g + (size_t)64 * Ks); \
  } while (0)
#define STAGE_B(dst_u16, gbase) do { \
    _Pragma("unroll") \
    for (int _j = 0; _j < NB; ++_j) { \
      int _idx = _j * 512 + tid; \
      int _br = _idx >> 3; \
      int _bs = (_idx & 7) ^ (_br & 7); \
      async16(&lds[(dst_u16) + _idx * 8], (gbase) + (size_t)_br * Ks + _bs * 8); \
    } \
  } while (0)
#define VM_P0 asm volatile("s_waitcnt vmcnt(%0)" :: "n"(NB + 2) : "memory")
#define VM_P1 asm volatile("s_waitcnt vmcnt(2)" ::: "memory")
#define VM_00 asm volatile("s_waitcnt vmcnt(0)" ::: "memory")
#define BARX  __builtin_amdgcn_s_barrier()

  // prologue tile 0, issue order: A0(2), B(NB), A1(2); A1 left outstanding
  STAGE_A(0,     Ag);
  STAGE_B(16384, Bg);
  STAGE_A(8192,  Ag + (size_t)128 * Ks);
  asm volatile("s_waitcnt vmcnt(2)" ::: "memory");   // A0 + B landed
  BARX;

  bf16x8 aF[4][2], bF[NB][2];
  for (int t = 0; t < nkt; ++t) {
    const int cb = (t & 1) ? SBUF : 0;
    const int sb = (t & 1) ? 0 : SBUF;
    const u16* An = Ag + (t + 1) * 64;
    const u16* Bn = Bg + (t + 1) * 64;
    const bool st = (t + 1 < nkt);
    // ---- P0: qa=0; reads A0 + B; stages A0', B' ----
#pragma unroll
    for (int mi = 0; mi < 4; ++mi) {
      aF[mi][0] = *(const bf16x8*)&lds[cb + aro + mi * 1024 + sl0];
      aF[mi][1] = *(const bf16x8*)&lds[cb + aro + mi * 1024 + sl1];
    }
#pragma unroll
    for (int ni = 0; ni < NB; ++ni) {
      bF[ni][0] = *(const bf16x8*)&lds[cb + 16384 + bro + ni * 1024 + sl0];
      bF[ni][1] = *(const bf16x8*)&lds[cb + 16384 + bro + ni * 1024 + sl1];
    }
    if (st) { STAGE_A(sb, An); STAGE_B(sb + 16384, Bn); VM_P0; } else { VM_00; }
    BARX;
    __builtin_amdgcn_s_setprio(1);
#pragma unroll
    for (int mi = 0; mi < 4; ++mi)
#pragma unroll
      for (int ni = 0; ni < NB; ++ni) {
        acc[0][mi][ni] = MFMA16(aF[mi][0], bF[ni][0], acc[0][mi][ni]);
        acc[0][mi][ni] = MFMA16(aF[mi][1], bF[ni][1], acc[0][mi][ni]);
      }
    __builtin_amdgcn_s_setprio(0);
    BARX;
    // ---- P1: qa=1; reads A1 (B cached); stages A1' ----
#pragma unroll
    for (int mi = 0; mi < 4; ++mi) {
      aF[mi][0] = *(const bf16x8*)&lds[cb + 8192 + aro + mi * 1024 + sl0];
      aF[mi][1] = *(const bf16x8*)&lds[cb + 8192 + aro + mi * 1024 + sl1];
    }
    if (st) { STAGE_A(sb + 8192, An + (size_t)128 * Ks); VM_P1; }
    BARX;
    __builtin_amdgcn_s_setprio(1);
#pragma unroll
    for (int mi = 0; mi < 4; ++mi)
#pragma unroll
      for (int ni = 0; ni < NB; ++ni) {
        acc[1][mi][ni] = MFMA16(aF[mi][0], bF[ni][0], acc[1][mi][ni]);
        acc[1][mi][ni] = MFMA16(aF[mi][1], bF[ni][1], acc[1][mi][ni]);
      }
    __builtin_amdgcn_s_setprio(0);
    BARX;
  }
#undef STAGE_A
#undef STAGE_B
#undef VM_P0
#undef VM_P1
#undef VM_00
#undef BARX
  // ---- epilogue: C/D layout col=lane&15, row=(lane>>4)*4+j (m89-verified) ----
#pragma unroll
  for (int qa = 0; qa < 2; ++qa)
#pragma unroll
    for (int mi = 0; mi < 4; ++mi)
#pragma unroll
      for (int ni = 0; ni < NB; ++ni) {
        int row = m0 + qa * 128 + wr * 64 + mi * 16 + lk * 4;
        int col = n0 + wc * (NB * 16) + ni * 16 + lrow;
        if (OUT_BF16) {
          u16* C = (u16*)Cout;
#pragma unroll
          for (int j = 0; j < 4; ++j)
            C[(size_t)(row + j) * Nst + col] = f2bf(acc[qa][mi][ni][j]);
        } else {
          float* C = (float*)Cout;
#pragma unroll
          for (int j = 0; j < 4; ++j)
            C[(size_t)(row + j) * Nst + col] = acc[qa][mi][ni][j];
        }
      }
}

// QKV projection: x[2048][4096] @ wqkv[6144][4096]^T -> QKV[2048][6144].
// NB=4: 256x256 tiles, grid 192 (1-D); XCD c (= bid%8) owns m-tile c.
__global__ __launch_bounds__(512, 2) void gemm256_qkv(const u16* __restrict__ xb,
                                                      const u16* __restrict__ wqkvb,
                                                      u16* __restrict__ QKVb) {
  const int bid = blockIdx.x;
  gemm256_body<4, 1>(xb, wqkvb, QKVb, (bid & 7) * 256, (bid >> 3) * 256, QST, 4096);
}

// output projection: AO[2048][4096] @ wo[4096][4096]^T -> out f32. grid (32,8).
__global__ __launch_bounds__(512, 2) void gemm256_wo(const u16* __restrict__ AOb,
                                                     const u16* __restrict__ wob,
                                                     float* __restrict__ out) {
  int lid = blockIdx.y * 32 + blockIdx.x;
  int swz = (lid & 7) * 32 + (lid >> 3);
  gemm256_body<2, 0>(AOb, wob, out, (swz >> 5) * 256, (swz & 31) * 128, 4096, 4096);
}

// ---------------- flash attention v3 + fused Q-RoPE ----------
// Swapped-operand 32x32, causal, GQA; K/V double-buffered; async staging;
// defer-max; one barrier per tile.  Q-RoPE applied in-register at load.
__global__ __launch_bounds__(256, 2) void attn_fwd3(const u16* __restrict__ QKVb,
                                                    u16* __restrict__ O,
                                                    const float* __restrict__ cosb,
                                                    const float* __restrict__ sinb) {
  __shared__ alignas(16) u16 Ks[2][64 * 128];    // [key][d], XOR-swizzled
  __shared__ alignas(16) u16 VTs[2][128 * 64];   // [d][kappa-pos], XOR-swizzled
  const u16* Km = QKVb + 4096;
  const u16* Vm = QKVb + 5120;
  const int tid = threadIdx.x;
  const int w = tid >> 6, lane = tid & 63;
  const int lq = lane & 31, hi = lane >> 5;
  const int bid = blockIdx.x;
  const int head = bid & 31;
  const int g = bid >> 5;
  const int qt = (g < 8) ? (15 - g) : (g - 8);   // long tiles dispatched first
  const int qt0 = qt * 128;
  const int hk = head >> 2;
  const float scale = 0.08838834764831845f;      // 1/sqrt(128)
  const int qw = qt0 + w * 32;
  const int qrow = qw + lq;

  // Q fragments (B-operand) with fused RoPE: chunk c covers d = c*16 + hi*8 + 0..7
  bf16x8 qf[8];
  {
    const u16* qp = QKVb + (size_t)qrow * QST + head * HD + hi * 8;
    const float* csr = cosb + qrow * 64;
    const float* snr = sinb + qrow * 64;
#pragma unroll
    for (int c = 0; c < 8; ++c) {
      bf16x8 raw = *(const bf16x8*)&qp[c * 16];
      const u16* re = (const u16*)&raw;
      u16 outv[8];
#pragma unroll
      for (int j = 0; j < 4; ++j) {
        int i = c * 8 + hi * 4 + j;
        float cc = csr[i], ss = snr[i];
        float te = bf2f(re[2 * j]), to = bf2f(re[2 * j + 1]);
        outv[2 * j]     = f2bf(te * cc - to * ss);
        outv[2 * j + 1] = f2bf(te * ss + to * cc);
      }
      qf[c] = *(bf16x8*)outv;
    }
  }
  f32x16 o_acc[4] = {};
  float m_r = -3.0e38f, l_r = 0.f;

  // V staging mapping: thread owns key-pair kp (keys 2kp,2kp+1) x d-block dbs..dbs+15
  const int kp = tid & 31;
  const int dbs = (tid >> 5) * 16;
  const int kap2 = ((2 * kp) & ~12) | (((2 * kp) & 4) << 1) | (((2 * kp) & 8) >> 1); // even

  uint4 rv[4];
#define STAGE_K(j0, buf) do { \
    _Pragma("unroll") \
    for (int _it = 0; _it < 4; ++_it) { \
      int _idx = _it * 256 + tid; \
      int _row = _idx >> 4, _s16 = _idx & 15; \
      const char* _src = (const char*)(Km + (size_t)((j0) + _row) * QST + hk * HD) \
                         + ((_s16 * 16) ^ ((_row & 7) << 4)); \
      async16(&Ks[buf][_idx * 8], _src); \
    } \
  } while (0)
#define LOAD_V(j0) do { \
    const u16* _v0 = Vm + (size_t)((j0) + 2 * kp) * QST + hk * HD + dbs; \
    rv[0] = *(const uint4*)_v0;       rv[1] = *(const uint4*)(_v0 + 8); \
    rv[2] = *(const uint4*)(_v0 + QST); rv[3] = *(const uint4*)(_v0 + QST + 8); \
  } while (0)
#define WRITE_V(buf) do { \
    const u16* _a = (const u16*)&rv[0]; \
    const u16* _b = (const u16*)&rv[2]; \
    _Pragma("unroll") \
    for (int _e = 0; _e < 16; ++_e) { \
      int _d = dbs + _e; \
      u32 _val = (u32)_a[_e] | ((u32)_b[_e] << 16); \
      *(u32*)((char*)VTs[buf] + _d * 128 + ((kap2 * 2) ^ ((_d & 7) << 4))) = _val; \
    } \
  } while (0)

  // prologue: tile 0 into buf 0
  STAGE_K(0, 0);
  LOAD_V(0);
  asm volatile("s_waitcnt vmcnt(0)" ::: "memory");
  WRITE_V(0);
  __syncthreads();

  const int NT = qt0 / 64 + 2;
  for (int t = 0; t < NT; ++t) {
    const int j0 = t * 64;
    const int cur = t & 1;
    const bool pre = (t + 1 < NT);
    if (pre) {                       // issue next-tile staging BEFORE compute
      STAGE_K(j0 + 64, 1 - cur);
      LOAD_V(j0 + 64);
    }
    if (j0 <= qw + 31) {
      // ---- QK^T (swapped): s rows = keys, cols = q ----
      f32x16 s0 = {}, s1 = {};
      const int kswz = (lq & 7) << 4;
      __builtin_amdgcn_s_setprio(1);
#pragma unroll
      for (int c = 0; c < 8; ++c) {
        int cbv = c * 32 + hi * 16;
        bf16x8 k0 = *(const bf16x8*)((const char*)Ks[cur] + lq * 256 + (cbv ^ kswz));
        bf16x8 k1 = *(const bf16x8*)((const char*)Ks[cur] + (32 + lq) * 256 + (cbv ^ kswz));
        s0 = __builtin_amdgcn_mfma_f32_32x32x16_bf16(k0, qf[c], s0, 0, 0, 0);
        s1 = __builtin_amdgcn_mfma_f32_32x32x16_bf16(k1, qf[c], s1, 0, 0, 0);
      }
      __builtin_amdgcn_s_setprio(0);
      // ---- softmax (per-lane: lane owns column q) ----
      float p0[16], p1[16];
      float tm = -3.0e38f;
      const bool domask = (j0 + 63 > qw);
#pragma unroll
      for (int r = 0; r < 16; ++r) {
        int kk = (r & 3) + 8 * (r >> 2) + 4 * hi;
        float a = s0[r] * scale;
        float b = s1[r] * scale;
        if (domask) {
          if (j0 + kk > qrow)      a = -3.0e38f;
          if (j0 + 32 + kk > qrow) b = -3.0e38f;
        }
        p0[r] = a; p1[r] = b;
        tm = fmaxf(tm, fmaxf(a, b));
      }
      tm = fmaxf(tm, __shfl_xor(tm, 32));
      // ---- defer-max (T13): only rescale when max grew by > 8 ----
      if (!__all(tm <= m_r + 8.f)) {
        float mnew = fmaxf(m_r, tm);
        float corr = __expf(m_r - mnew);
        m_r = mnew;
        l_r *= corr;
#pragma unroll
        for (int dt = 0; dt < 4; ++dt)
#pragma unroll
          for (int r = 0; r < 16; ++r) o_acc[dt][r] *= corr;
      }
      float rs = 0.f;
#pragma unroll
      for (int r = 0; r < 16; ++r) {
        p0[r] = __expf(p0[r] - m_r);
        p1[r] = __expf(p1[r] - m_r);
        rs += p0[r] + p1[r];
      }
      rs += __shfl_xor(rs, 32);
      l_r += rs;
      // ---- pack P (own-lane kappa order) ----
      uint4 pk[4];
#pragma unroll
      for (int cc = 0; cc < 2; ++cc) {
        asm("v_cvt_pk_bf16_f32 %0, %1, %2" : "=v"(pk[cc].x)     : "v"(p0[8*cc+0]), "v"(p0[8*cc+1]));
        asm("v_cvt_pk_bf16_f32 %0, %1, %2" : "=v"(pk[cc].y)     : "v"(p0[8*cc+2]), "v"(p0[8*cc+3]));
        asm("v_cvt_pk_bf16_f32 %0, %1, %2" : "=v"(pk[cc].z)     : "v"(p0[8*cc+4]), "v"(p0[8*cc+5]));
        asm("v_cvt_pk_bf16_f32 %0, %1, %2" : "=v"(pk[cc].w)     : "v"(p0[8*cc+6]), "v"(p0[8*cc+7]));
        asm("v_cvt_pk_bf16_f32 %0, %1, %2" : "=v"(pk[2+cc].x)   : "v"(p1[8*cc+0]), "v"(p1[8*cc+1]));
        asm("v_cvt_pk_bf16_f32 %0, %1, %2" : "=v"(pk[2+cc].y)   : "v"(p1[8*cc+2]), "v"(p1[8*cc+3]));
        asm("v_cvt_pk_bf16_f32 %0, %1, %2" : "=v"(pk[2+cc].z)   : "v"(p1[8*cc+4]), "v"(p1[8*cc+5]));
        asm("v_cvt_pk_bf16_f32 %0, %1, %2" : "=v"(pk[2+cc].w)   : "v"(p1[8*cc+6]), "v"(p1[8*cc+7]));
      }
      // ---- PV: O[dt] += mfma(V^T-frag, P^T-frag) ----
      __builtin_amdgcn_s_setprio(1);
#pragma unroll
      for (int dt = 0; dt < 4; ++dt) {
        const char* vrow = (const char*)VTs[cur] + (dt * 32 + lq) * 128;
#pragma unroll
        for (int c = 0; c < 4; ++c) {
          bf16x8 vf = *(const bf16x8*)(vrow + ((c * 32 + hi * 16) ^ kswz));
          bf16x8 pf = __builtin_bit_cast(bf16x8, pk[c]);
          o_acc[dt] = __builtin_amdgcn_mfma_f32_32x32x16_bf16(vf, pf, o_acc[dt], 0, 0, 0);
        }
      }
      __builtin_amdgcn_s_setprio(0);
    }
    if (pre) {
      asm volatile("s_waitcnt vmcnt(0)" ::: "memory");  // K dma + V regs landed
      WRITE_V(1 - cur);
    }
    __syncthreads();
  }
#undef STAGE_K
#undef LOAD_V
#undef WRITE_V
  // ---- normalize + write (O stride = DIM) ----
  float inv = 1.0f / l_r;
  u16* op = O + (size_t)qrow * DIM + head * HD;
#pragma unroll
  for (int dt = 0; dt < 4; ++dt)
#pragma unroll
    for (int rq = 0; rq < 4; ++rq) {
      int d0 = dt * 32 + 8 * rq + 4 * hi;
      ushort4 o4;
      o4.x = f2bf(o_acc[dt][4 * rq + 0] * inv);
      o4.y = f2bf(o_acc[dt][4 * rq + 1] * inv);
      o4.z = f2bf(o_acc[dt][4 * rq + 2] * inv);
      o4.w = f2bf(o_acc[dt][4 * rq + 3] * inv);
      *(ushort4*)&op[d0] = o4;
    }
}

// ---------------- host launcher ----------------
extern "C" void kernel_launch(void* const* d_in, const int* in_sizes, int n_in,
                              void* d_out, int out_size, void* d_ws, size_t ws_size,
                              hipStream_t stream) {
  (void)in_sizes; (void)n_in; (void)out_size;
  const float* x  = (const float*)d_in[0];
  const float* wq = (const float*)d_in[2];
  const float* wk = (const float*)d_in[3];
  const float* wv = (const float*)d_in[4];
  const float* wo = (const float*)d_in[5];

  char* ws = (char*)d_ws;
  u16*   xb    = (u16*)(ws + 0);                      // 16 MB
  u16*   wqkvb = (u16*)(ws + 16777216ull);            // 48 MB [6144][4096]
  u16*   wob   = (u16*)(ws + 67108864ull);            // 32 MB
  u16*   QKVb  = (u16*)(ws + 100663296ull);           // 24 MB [2048][6144]
  u16*   AOb   = (u16*)(ws + 125829120ull);           // 16 MB [2048][4096]
  float* cosb  = (float*)(ws + 142606336ull);         // 512 KB
  float* sinb  = (float*)(ws + 143130624ull);         // 512 KB
  if (ws_size < 143654912ull) return;

  conv_all<<<2048, 256, 0, stream>>>(x, wq, wk, wv, wo, xb, wqkvb, wob, cosb, sinb);

  gemm256_qkv<<<192, 512, 0, stream>>>(xb, wqkvb, QKVb);

  rope_k<<<4096, 256, 0, stream>>>(QKVb, cosb, sinb);

  attn_fwd3<<<512, 256, 0, stream>>>(QKVb, AOb, cosb, sinb);

  gemm256_wo<<<dim3(32, 8), 512, 0, stream>>>(AOb, wob, (float*)d_out);
}

// Round 11
// 315.618 us; speedup vs baseline: 1.0485x; 1.0485x over previous
//
#include <hip/hip_runtime.h>

#define S_LEN 2048
#define DIM   4096
#define NH    32
#define NKV   8
#define HD    128
#define QST   6144   // packed QKV row stride (Q | K | V)

typedef unsigned short u16;
typedef unsigned int   u32;
typedef __bf16 bf16x8 __attribute__((ext_vector_type(8)));
typedef float  f32x4  __attribute__((ext_vector_type(4)));
typedef float  f32x16 __attribute__((ext_vector_type(16)));

__device__ __forceinline__ u16 f2bf(float f) {
  unsigned u = __float_as_uint(f);
  u += 0x7FFFu + ((u >> 16) & 1u);   // RNE
  return (u16)(u >> 16);
}
__device__ __forceinline__ float bf2f(u16 v) {
  return __uint_as_float(((unsigned)v) << 16);
}
__device__ __forceinline__ void async16(void* lds, const void* g) {
  __builtin_amdgcn_global_load_lds((const __attribute__((address_space(1))) void*)g,
                                   (__attribute__((address_space(3))) void*)lds,
                                   16, 0, 0);
}
#define MFMA16(a, b, c) __builtin_amdgcn_mfma_f32_16x16x32_bf16((a), (b), (c), 0, 0, 0)

// ------------- fused f32->bf16 convert (all 5 tensors) + RoPE table -------------
__global__ void conv_all(const float* __restrict__ x,  const float* __restrict__ wq,
                         const float* __restrict__ wk, const float* __restrict__ wv,
                         const float* __restrict__ wo,
                         u16* __restrict__ xb, u16* __restrict__ wqkvb,
                         u16* __restrict__ wob,
                         float* __restrict__ cs, float* __restrict__ sn) {
  const int stride = gridDim.x * blockDim.x;
  for (int i = blockIdx.x * blockDim.x + threadIdx.x; i < 12713984; i += stride) {
    if (i < 12582912) {
      const float* src; u16* dst; int off;
      if (i < 2097152)      { src = x;  dst = xb;               off = i; }
      else if (i < 6291456) { src = wq; dst = wqkvb;            off = i - 2097152; }
      else if (i < 7340032) { src = wk; dst = wqkvb + 16777216; off = i - 6291456; }
      else if (i < 8388608) { src = wv; dst = wqkvb + 20971520; off = i - 7340032; }
      else                  { src = wo; dst = wob;              off = i - 8388608; }
      float4 v = ((const float4*)src)[off];
      ((ushort4*)dst)[off] = make_ushort4(f2bf(v.x), f2bf(v.y), f2bf(v.z), f2bf(v.w));
    } else {
      int li = i - 12582912;            // RoPE table: S_LEN*64 entries
      int fi = li & 63, t = li >> 6;
      float freq = powf(500000.0f, -(float)(2 * fi) / 128.0f);
      float ang = (float)t * freq;
      cs[li] = cosf(ang);
      sn[li] = sinf(ang);
    }
  }
}

// ---------------- RoPE in-place on packed QKV, K region only ----------------
// (Q-RoPE is fused into attn's Q load.)
__global__ void rope_k(u16* __restrict__ QKVb, const float* __restrict__ cs,
                       const float* __restrict__ sn) {
  int idx = blockIdx.x * blockDim.x + threadIdx.x;
  if (idx >= 1048576) return;
  int i = idx & 63;
  int tmp = idx >> 6;
  int hh = tmp & 7;
  int t  = tmp >> 3;
  u16* p = QKVb + (size_t)t * QST + 4096 + hh * HD + 2 * i;
  float c = cs[t * 64 + i], s = sn[t * 64 + i];
  float te = bf2f(p[0]), to = bf2f(p[1]);
  p[0] = f2bf(te * c - to * s);
  p[1] = f2bf(te * s + to * c);
}

// ======== 256 x (NB*64) 8-wave GEMM, BK=64, 2 phases/K-tile, counted vmcnt ====
// (Best-known config: NB=3 qkv 119-120 us, MfmaUtil 36%, 0 bank conflicts.
//  NB=4/32x32/4-phase variants all regressed -- GEMM closed at this plateau.)
// Wait-chain (audited): prologue vmcnt(2) leaves A1-tail; P0 vmcnt(NB+2)
// retires old A1'; P1 vmcnt(2) retires A0''+B'', leaves A1''.  Never 0 mid-loop.
template<int NB, int OUT_BF16>
__device__ __forceinline__ void gemm256_body(const u16* __restrict__ A,
                                             const u16* __restrict__ Bm,
                                             void* __restrict__ Cout,
                                             int m0, int n0, int Nst, int Ks) {
  constexpr int BSZ  = NB * 4096;        // B u16 per buffer
  constexpr int SBUF = 16384 + BSZ;      // u16 per buffer
  __shared__ alignas(16) u16 lds[2 * SBUF];
  const int tid = threadIdx.x;
  const int w = tid >> 6, lane = tid & 63;
  const int lrow = lane & 15, lk = lane >> 4;
  const int wr = w >> 2, wc = w & 3;
  f32x4 acc[2][4][NB] = {};

  const int srow = tid >> 3;                 // staging row 0..63
  const int scol = (tid & 7) ^ (srow & 7);   // pre-swizzled source 16B slot
  const u16* Ag = A + (size_t)m0 * Ks;
  const u16* Bg = Bm + (size_t)n0 * Ks;

  const int sl0 = (lk ^ (lrow & 7)) * 8;     // kk=0 swizzled slot (u16)
  const int sl1 = ((4 + lk) ^ (lrow & 7)) * 8;
  const int aro = (wr * 64 + lrow) * 64;     // + mi*1024, within 128-row half
  const int bro = (wc * (NB * 16) + lrow) * 64;  // + ni*1024
  const int nkt = Ks >> 6;

#define STAGE_A(dst_u16, gbase) do { \
    const u16* _g = (gbase) + (size_t)srow * Ks + scol * 8; \
    async16(&lds[(dst_u16) + tid * 8], _g); \
    async16(&lds[(dst_u16) + tid * 8 + 4096], _g + (size_t)64 * Ks); \
  } while (0)
#define STAGE_B(dst_u16, gbase) do { \
    _Pragma("unroll") \
    for (int _j = 0; _j < NB; ++_j) { \
      int _idx = _j * 512 + tid; \
      int _br = _idx >> 3; \
      int _bs = (_idx & 7) ^ (_br & 7); \
      async16(&lds[(dst_u16) + _idx * 8], (gbase) + (size_t)_br * Ks + _bs * 8); \
    } \
  } while (0)
#define VM_P0 asm volatile("s_waitcnt vmcnt(%0)" :: "n"(NB + 2) : "memory")
#define VM_P1 asm volatile("s_waitcnt vmcnt(2)" ::: "memory")
#define VM_00 asm volatile("s_waitcnt vmcnt(0)" ::: "memory")
#define BARX  __builtin_amdgcn_s_barrier()

  // prologue tile 0, issue order: A0(2), B(NB), A1(2); A1 left outstanding
  STAGE_A(0,     Ag);
  STAGE_B(16384, Bg);
  STAGE_A(8192,  Ag + (size_t)128 * Ks);
  asm volatile("s_waitcnt vmcnt(2)" ::: "memory");   // A0 + B landed
  BARX;

  bf16x8 aF[4][2], bF[NB][2];
  for (int t = 0; t < nkt; ++t) {
    const int cb = (t & 1) ? SBUF : 0;
    const int sb = (t & 1) ? 0 : SBUF;
    const u16* An = Ag + (t + 1) * 64;
    const u16* Bn = Bg + (t + 1) * 64;
    const bool st = (t + 1 < nkt);
    // ---- P0: qa=0; reads A0 + B; stages A0', B' ----
#pragma unroll
    for (int mi = 0; mi < 4; ++mi) {
      aF[mi][0] = *(const bf16x8*)&lds[cb + aro + mi * 1024 + sl0];
      aF[mi][1] = *(const bf16x8*)&lds[cb + aro + mi * 1024 + sl1];
    }
#pragma unroll
    for (int ni = 0; ni < NB; ++ni) {
      bF[ni][0] = *(const bf16x8*)&lds[cb + 16384 + bro + ni * 1024 + sl0];
      bF[ni][1] = *(const bf16x8*)&lds[cb + 16384 + bro + ni * 1024 + sl1];
    }
    if (st) { STAGE_A(sb, An); STAGE_B(sb + 16384, Bn); VM_P0; } else { VM_00; }
    BARX;
    __builtin_amdgcn_s_setprio(1);
#pragma unroll
    for (int mi = 0; mi < 4; ++mi)
#pragma unroll
      for (int ni = 0; ni < NB; ++ni) {
        acc[0][mi][ni] = MFMA16(aF[mi][0], bF[ni][0], acc[0][mi][ni]);
        acc[0][mi][ni] = MFMA16(aF[mi][1], bF[ni][1], acc[0][mi][ni]);
      }
    __builtin_amdgcn_s_setprio(0);
    BARX;
    // ---- P1: qa=1; reads A1 (B cached); stages A1' ----
#pragma unroll
    for (int mi = 0; mi < 4; ++mi) {
      aF[mi][0] = *(const bf16x8*)&lds[cb + 8192 + aro + mi * 1024 + sl0];
      aF[mi][1] = *(const bf16x8*)&lds[cb + 8192 + aro + mi * 1024 + sl1];
    }
    if (st) { STAGE_A(sb + 8192, An + (size_t)128 * Ks); VM_P1; }
    BARX;
    __builtin_amdgcn_s_setprio(1);
#pragma unroll
    for (int mi = 0; mi < 4; ++mi)
#pragma unroll
      for (int ni = 0; ni < NB; ++ni) {
        acc[1][mi][ni] = MFMA16(aF[mi][0], bF[ni][0], acc[1][mi][ni]);
        acc[1][mi][ni] = MFMA16(aF[mi][1], bF[ni][1], acc[1][mi][ni]);
      }
    __builtin_amdgcn_s_setprio(0);
    BARX;
  }
#undef STAGE_A
#undef STAGE_B
#undef VM_P0
#undef VM_P1
#undef VM_00
#undef BARX
  // ---- epilogue: C/D layout col=lane&15, row=(lane>>4)*4+j (m89-verified) ----
#pragma unroll
  for (int qa = 0; qa < 2; ++qa)
#pragma unroll
    for (int mi = 0; mi < 4; ++mi)
#pragma unroll
      for (int ni = 0; ni < NB; ++ni) {
        int row = m0 + qa * 128 + wr * 64 + mi * 16 + lk * 4;
        int col = n0 + wc * (NB * 16) + ni * 16 + lrow;
        if (OUT_BF16) {
          u16* C = (u16*)Cout;
#pragma unroll
          for (int j = 0; j < 4; ++j)
            C[(size_t)(row + j) * Nst + col] = f2bf(acc[qa][mi][ni][j]);
        } else {
          float* C = (float*)Cout;
#pragma unroll
          for (int j = 0; j < 4; ++j)
            C[(size_t)(row + j) * Nst + col] = acc[qa][mi][ni][j];
        }
      }
}

// QKV projection: x[2048][4096] @ wqkv[6144][4096]^T -> QKV[2048][6144].
// NB=3 (best-known): grid (32,8) = 256 blocks; XCD-pinned m-row via swz.
__global__ __launch_bounds__(512, 2) void gemm256_qkv(const u16* __restrict__ xb,
                                                      const u16* __restrict__ wqkvb,
                                                      u16* __restrict__ QKVb) {
  int lid = blockIdx.y * 32 + blockIdx.x;
  int swz = (lid & 7) * 32 + (lid >> 3);
  gemm256_body<3, 1>(xb, wqkvb, QKVb, (swz >> 5) * 256, (swz & 31) * 192, QST, 4096);
}

// output projection: AO[2048][4096] @ wo[4096][4096]^T -> out f32. grid (32,8).
__global__ __launch_bounds__(512, 2) void gemm256_wo(const u16* __restrict__ AOb,
                                                     const u16* __restrict__ wob,
                                                     float* __restrict__ out) {
  int lid = blockIdx.y * 32 + blockIdx.x;
  int swz = (lid & 7) * 32 + (lid >> 3);
  gemm256_body<2, 0>(AOb, wob, out, (swz >> 5) * 256, (swz & 31) * 128, 4096, 4096);
}

// ---------------- flash attention v3 + fused Q-RoPE + KV/XCD affinity --------
// Swapped-operand 32x32, causal, GQA; K/V double-buffered; async staging;
// defer-max; one barrier per tile.
// Block remap (r10): hk = bid&7 -- with round-robin bid%8 -> XCD placement,
// each XCD serves exactly ONE KV group (2 MB K+V, fits its 4 MB L2), so the
// 4 heads sharing a group hit L2 instead of re-fetching HBM.
__global__ __launch_bounds__(256, 2) void attn_fwd3(const u16* __restrict__ QKVb,
                                                    u16* __restrict__ O,
                                                    const float* __restrict__ cosb,
                                                    const float* __restrict__ sinb) {
  __shared__ alignas(16) u16 Ks[2][64 * 128];    // [key][d], XOR-swizzled
  __shared__ alignas(16) u16 VTs[2][128 * 64];   // [d][kappa-pos], XOR-swizzled
  const u16* Km = QKVb + 4096;
  const u16* Vm = QKVb + 5120;
  const int tid = threadIdx.x;
  const int w = tid >> 6, lane = tid & 63;
  const int lq = lane & 31, hi = lane >> 5;
  const int bid = blockIdx.x;
  const int hk   = bid & 7;                      // KV group == XCD
  const int head = hk * 4 + ((bid >> 3) & 3);
  const int g = bid >> 5;
  const int qt = (g < 8) ? (15 - g) : (g - 8);   // long tiles dispatched first
  const int qt0 = qt * 128;
  const float scale = 0.08838834764831845f;      // 1/sqrt(128)
  const int qw = qt0 + w * 32;
  const int qrow = qw + lq;

  // Q fragments (B-operand) with fused RoPE: chunk c covers d = c*16 + hi*8 + 0..7
  bf16x8 qf[8];
  {
    const u16* qp = QKVb + (size_t)qrow * QST + head * HD + hi * 8;
    const float* csr = cosb + qrow * 64;
    const float* snr = sinb + qrow * 64;
#pragma unroll
    for (int c = 0; c < 8; ++c) {
      bf16x8 raw = *(const bf16x8*)&qp[c * 16];
      const u16* re = (const u16*)&raw;
      u16 outv[8];
#pragma unroll
      for (int j = 0; j < 4; ++j) {
        int i = c * 8 + hi * 4 + j;
        float cc = csr[i], ss = snr[i];
        float te = bf2f(re[2 * j]), to = bf2f(re[2 * j + 1]);
        outv[2 * j]     = f2bf(te * cc - to * ss);
        outv[2 * j + 1] = f2bf(te * ss + to * cc);
      }
      qf[c] = *(bf16x8*)outv;
    }
  }
  f32x16 o_acc[4] = {};
  float m_r = -3.0e38f, l_r = 0.f;

  // V staging mapping: thread owns key-pair kp (keys 2kp,2kp+1) x d-block dbs..dbs+15
  const int kp = tid & 31;
  const int dbs = (tid >> 5) * 16;
  const int kap2 = ((2 * kp) & ~12) | (((2 * kp) & 4) << 1) | (((2 * kp) & 8) >> 1); // even

  uint4 rv[4];
#define STAGE_K(j0, buf) do { \
    _Pragma("unroll") \
    for (int _it = 0; _it < 4; ++_it) { \
      int _idx = _it * 256 + tid; \
      int _row = _idx >> 4, _s16 = _idx & 15; \
      const char* _src = (const char*)(Km + (size_t)((j0) + _row) * QST + hk * HD) \
                         + ((_s16 * 16) ^ ((_row & 7) << 4)); \
      async16(&Ks[buf][_idx * 8], _src); \
    } \
  } while (0)
#define LOAD_V(j0) do { \
    const u16* _v0 = Vm + (size_t)((j0) + 2 * kp) * QST + hk * HD + dbs; \
    rv[0] = *(const uint4*)_v0;       rv[1] = *(const uint4*)(_v0 + 8); \
    rv[2] = *(const uint4*)(_v0 + QST); rv[3] = *(const uint4*)(_v0 + QST + 8); \
  } while (0)
#define WRITE_V(buf) do { \
    const u16* _a = (const u16*)&rv[0]; \
    const u16* _b = (const u16*)&rv[2]; \
    _Pragma("unroll") \
    for (int _e = 0; _e < 16; ++_e) { \
      int _d = dbs + _e; \
      u32 _val = (u32)_a[_e] | ((u32)_b[_e] << 16); \
      *(u32*)((char*)VTs[buf] + _d * 128 + ((kap2 * 2) ^ ((_d & 7) << 4))) = _val; \
    } \
  } while (0)

  // prologue: tile 0 into buf 0
  STAGE_K(0, 0);
  LOAD_V(0);
  asm volatile("s_waitcnt vmcnt(0)" ::: "memory");
  WRITE_V(0);
  __syncthreads();

  const int NT = qt0 / 64 + 2;
  for (int t = 0; t < NT; ++t) {
    const int j0 = t * 64;
    const int cur = t & 1;
    const bool pre = (t + 1 < NT);
    if (pre) {                       // issue next-tile staging BEFORE compute
      STAGE_K(j0 + 64, 1 - cur);
      LOAD_V(j0 + 64);
    }
    if (j0 <= qw + 31) {
      // ---- QK^T (swapped): s rows = keys, cols = q ----
      f32x16 s0 = {}, s1 = {};
      const int kswz = (lq & 7) << 4;
      __builtin_amdgcn_s_setprio(1);
#pragma unroll
      for (int c = 0; c < 8; ++c) {
        int cbv = c * 32 + hi * 16;
        bf16x8 k0 = *(const bf16x8*)((const char*)Ks[cur] + lq * 256 + (cbv ^ kswz));
        bf16x8 k1 = *(const bf16x8*)((const char*)Ks[cur] + (32 + lq) * 256 + (cbv ^ kswz));
        s0 = __builtin_amdgcn_mfma_f32_32x32x16_bf16(k0, qf[c], s0, 0, 0, 0);
        s1 = __builtin_amdgcn_mfma_f32_32x32x16_bf16(k1, qf[c], s1, 0, 0, 0);
      }
      __builtin_amdgcn_s_setprio(0);
      // ---- softmax (per-lane: lane owns column q) ----
      float p0[16], p1[16];
      float tm = -3.0e38f;
      const bool domask = (j0 + 63 > qw);
#pragma unroll
      for (int r = 0; r < 16; ++r) {
        int kk = (r & 3) + 8 * (r >> 2) + 4 * hi;
        float a = s0[r] * scale;
        float b = s1[r] * scale;
        if (domask) {
          if (j0 + kk > qrow)      a = -3.0e38f;
          if (j0 + 32 + kk > qrow) b = -3.0e38f;
        }
        p0[r] = a; p1[r] = b;
        tm = fmaxf(tm, fmaxf(a, b));
      }
      tm = fmaxf(tm, __shfl_xor(tm, 32));
      // ---- defer-max (T13): only rescale when max grew by > 8 ----
      if (!__all(tm <= m_r + 8.f)) {
        float mnew = fmaxf(m_r, tm);
        float corr = __expf(m_r - mnew);
        m_r = mnew;
        l_r *= corr;
#pragma unroll
        for (int dt = 0; dt < 4; ++dt)
#pragma unroll
          for (int r = 0; r < 16; ++r) o_acc[dt][r] *= corr;
      }
      float rs = 0.f;
#pragma unroll
      for (int r = 0; r < 16; ++r) {
        p0[r] = __expf(p0[r] - m_r);
        p1[r] = __expf(p1[r] - m_r);
        rs += p0[r] + p1[r];
      }
      rs += __shfl_xor(rs, 32);
      l_r += rs;
      // ---- pack P (own-lane kappa order) ----
      uint4 pk[4];
#pragma unroll
      for (int cc = 0; cc < 2; ++cc) {
        asm("v_cvt_pk_bf16_f32 %0, %1, %2" : "=v"(pk[cc].x)     : "v"(p0[8*cc+0]), "v"(p0[8*cc+1]));
        asm("v_cvt_pk_bf16_f32 %0, %1, %2" : "=v"(pk[cc].y)     : "v"(p0[8*cc+2]), "v"(p0[8*cc+3]));
        asm("v_cvt_pk_bf16_f32 %0, %1, %2" : "=v"(pk[cc].z)     : "v"(p0[8*cc+4]), "v"(p0[8*cc+5]));
        asm("v_cvt_pk_bf16_f32 %0, %1, %2" : "=v"(pk[cc].w)     : "v"(p0[8*cc+6]), "v"(p0[8*cc+7]));
        asm("v_cvt_pk_bf16_f32 %0, %1, %2" : "=v"(pk[2+cc].x)   : "v"(p1[8*cc+0]), "v"(p1[8*cc+1]));
        asm("v_cvt_pk_bf16_f32 %0, %1, %2" : "=v"(pk[2+cc].y)   : "v"(p1[8*cc+2]), "v"(p1[8*cc+3]));
        asm("v_cvt_pk_bf16_f32 %0, %1, %2" : "=v"(pk[2+cc].z)   : "v"(p1[8*cc+4]), "v"(p1[8*cc+5]));
        asm("v_cvt_pk_bf16_f32 %0, %1, %2" : "=v"(pk[2+cc].w)   : "v"(p1[8*cc+6]), "v"(p1[8*cc+7]));
      }
      // ---- PV: O[dt] += mfma(V^T-frag, P^T-frag) ----
      __builtin_amdgcn_s_setprio(1);
#pragma unroll
      for (int dt = 0; dt < 4; ++dt) {
        const char* vrow = (const char*)VTs[cur] + (dt * 32 + lq) * 128;
#pragma unroll
        for (int c = 0; c < 4; ++c) {
          bf16x8 vf = *(const bf16x8*)(vrow + ((c * 32 + hi * 16) ^ kswz));
          bf16x8 pf = __builtin_bit_cast(bf16x8, pk[c]);
          o_acc[dt] = __builtin_amdgcn_mfma_f32_32x32x16_bf16(vf, pf, o_acc[dt], 0, 0, 0);
        }
      }
      __builtin_amdgcn_s_setprio(0);
    }
    if (pre) {
      asm volatile("s_waitcnt vmcnt(0)" ::: "memory");  // K dma + V regs landed
      WRITE_V(1 - cur);
    }
    __syncthreads();
  }
#undef STAGE_K
#undef LOAD_V
#undef WRITE_V
  // ---- normalize + write (O stride = DIM) ----
  float inv = 1.0f / l_r;
  u16* op = O + (size_t)qrow * DIM + head * HD;
#pragma unroll
  for (int dt = 0; dt < 4; ++dt)
#pragma unroll
    for (int rq = 0; rq < 4; ++rq) {
      int d0 = dt * 32 + 8 * rq + 4 * hi;
      ushort4 o4;
      o4.x = f2bf(o_acc[dt][4 * rq + 0] * inv);
      o4.y = f2bf(o_acc[dt][4 * rq + 1] * inv);
      o4.z = f2bf(o_acc[dt][4 * rq + 2] * inv);
      o4.w = f2bf(o_acc[dt][4 * rq + 3] * inv);
      *(ushort4*)&op[d0] = o4;
    }
}

// ---------------- host launcher ----------------
extern "C" void kernel_launch(void* const* d_in, const int* in_sizes, int n_in,
                              void* d_out, int out_size, void* d_ws, size_t ws_size,
                              hipStream_t stream) {
  (void)in_sizes; (void)n_in; (void)out_size;
  const float* x  = (const float*)d_in[0];
  const float* wq = (const float*)d_in[2];
  const float* wk = (const float*)d_in[3];
  const float* wv = (const float*)d_in[4];
  const float* wo = (const float*)d_in[5];

  char* ws = (char*)d_ws;
  u16*   xb    = (u16*)(ws + 0);                      // 16 MB
  u16*   wqkvb = (u16*)(ws + 16777216ull);            // 48 MB [6144][4096]
  u16*   wob   = (u16*)(ws + 67108864ull);            // 32 MB
  u16*   QKVb  = (u16*)(ws + 100663296ull);           // 24 MB [2048][6144]
  u16*   AOb   = (u16*)(ws + 125829120ull);           // 16 MB [2048][4096]
  float* cosb  = (float*)(ws + 142606336ull);         // 512 KB
  float* sinb  = (float*)(ws + 143130624ull);         // 512 KB
  if (ws_size < 143654912ull) return;

  conv_all<<<2048, 256, 0, stream>>>(x, wq, wk, wv, wo, xb, wqkvb, wob, cosb, sinb);

  gemm256_qkv<<<dim3(32, 8), 512, 0, stream>>>(xb, wqkvb, QKVb);

  rope_k<<<4096, 256, 0, stream>>>(QKVb, cosb, sinb);

  attn_fwd3<<<512, 256, 0, stream>>>(QKVb, AOb, cosb, sinb);

  gemm256_wo<<<dim3(32, 8), 512, 0, stream>>>(AOb, wob, (float*)d_out);
}